// Round 1
// baseline (510.811 us; speedup 1.0000x reference)
//
#include <hip/hip_runtime.h>

// GraphVAE: GCN-VAE encoder + edge decoder + 50-iter MPM fixed point, fused
// into ONE persistent 20-block kernel with a custom device-scope barrier.
//
// Key facts exploited (see round-0 analysis):
//  * S[i,j,a,b] = A[i,j]*B[a,b] off-diagonal (dA=dB=1) -> MPM step is
//      Xn[i,a] = ns[i,a]*X[i,a] + sum_{j!=i} A[i,j]*max_{b!=a} X[j,b]*B[a,b]
//  * node_logits / Wn1 / Wn2 are DEAD (B diag forced to 1 after sigmoid).
//  * f is positively homogeneous and X>0 -> normalization applied one step
//    late as a scalar => exactly ONE grid barrier per MPM iteration.
//  * X>0 -> "b!=a" exclusion == zeroing one element of the cached B row.

#define NN 80
#define PBLK 20            // blocks (each owns 4 columns of X) - all co-resident
#define TPB 320            // 5 full waves; lane <-> one (i,a) output
#define RP 84              // LDS row pad: 84 mod 32 = 20 -> conflict-free b128
#define NCOLS 13           // max owned feature columns per block (256/20 rounded up)

__device__ __forceinline__ void gbar(int* ctr, int target){
  __syncthreads();
  if (threadIdx.x == 0){
    __hip_atomic_fetch_add(ctr, 1, __ATOMIC_RELEASE, __HIP_MEMORY_SCOPE_AGENT);
    while (__hip_atomic_load(ctr, __ATOMIC_ACQUIRE, __HIP_MEMORY_SCOPE_AGENT) < target)
      __builtin_amdgcn_s_sleep(1);
  }
  __syncthreads();
}

__device__ __forceinline__ float wave_sum(float v){
  #pragma unroll
  for (int k = 32; k >= 1; k >>= 1) v += __shfl_xor(v, k, 64);
  return v;
}

// GCN aggregate (+self loop) + bias + BatchNorm(train, biased var) + ReLU for
// this block's owned feature columns. inL: LDS [NCOLS][80] (pre-aggregation,
// own columns). outT: global transposed [256][80].
__device__ void gcn_bn_relu(const float* inL, float* outT,
                            const float* bias, const float* gamma, const float* beta,
                            const int* ei, const float* dinv,
                            float* accL, float* colstat, int p, int tid)
{
  for (int u = tid; u < NCOLS*NN; u += TPB) accL[u] = 0.f;
  __syncthreads();
  for (int cl = 0; cl < NCOLS; cl++){
    int c = p + PBLK*cl; if (c >= 256) break;
    const float* col = &inL[cl*NN];
    for (int e = tid; e < 800; e += TPB){
      int sidx = ei[e], didx = ei[800+e];
      atomicAdd(&accL[cl*NN + didx], col[sidx]*dinv[sidx]*dinv[didx]);
    }
  }
  __syncthreads();
  for (int u = tid; u < NCOLS*NN; u += TPB){
    int cl = u/NN, i = u - cl*NN, c = p + PBLK*cl;
    if (c < 256) accL[u] += inL[cl*NN+i]*dinv[i]*dinv[i] + bias[c];
  }
  __syncthreads();
  if (tid < NCOLS){
    int c = p + PBLK*tid;
    if (c < 256){
      const float* a = &accL[tid*NN];
      float m = 0.f;
      for (int i = 0; i < NN; i++) m += a[i];
      m *= (1.0f/NN);
      float v = 0.f;
      for (int i = 0; i < NN; i++){ float d = a[i]-m; v += d*d; }
      v *= (1.0f/NN);
      colstat[2*tid]   = m;
      colstat[2*tid+1] = 1.0f/sqrtf(v + 1e-5f);
    }
  }
  __syncthreads();
  for (int u = tid; u < NCOLS*NN; u += TPB){
    int cl = u/NN, i = u - cl*NN, c = p + PBLK*cl;
    if (c < 256){
      float hv = gamma[c]*(accL[u]-colstat[2*cl])*colstat[2*cl+1] + beta[c];
      outT[c*NN+i] = fmaxf(hv, 0.f);
    }
  }
}

__global__ __launch_bounds__(TPB, 1) void gvae_fused(
    const float* __restrict__ x,  const int* __restrict__ ei, const int* __restrict__ adj,
    const float* __restrict__ eps,
    const float* __restrict__ W1, const float* __restrict__ b1, const float* __restrict__ g1, const float* __restrict__ bt1,
    const float* __restrict__ W2, const float* __restrict__ b2, const float* __restrict__ g2, const float* __restrict__ bt2,
    const float* __restrict__ Wmu,const float* __restrict__ bmu,const float* __restrict__ Wlv,const float* __restrict__ blv,
    const float* __restrict__ We1,const float* __restrict__ be1,const float* __restrict__ We2,const float* __restrict__ be2,
    float* __restrict__ out, float* __restrict__ ws)
{
  const int tid = threadIdx.x;
  const int p   = blockIdx.x;

  // workspace layout (floats)
  int*   ctr   = (int*)ws;        // [0]     barrier counter (memset 0 by host)
  float* sumsq = ws + 16;         // [51]    per-iteration ||R||^2 (memset 0)
  float* hT    = ws + 128;        // [256*80] layer-1 output, transposed
  float* h2T   = hT  + 20480;     // [256*80] layer-2 output, transposed
  float* Bm    = h2T + 20480;     // [80*80]  B = sigmoid(A_hat), diag=1
  float* Xb0   = Bm  + 6400;      // [80*80]  MPM ping
  float* Xb1   = Xb0 + 6400;      // [80*80]  MPM pong

  __shared__ float Xs[NN*RP];        // MPM: X tile (row pad 84)
  __shared__ float MtL[4*RP];        // MPM: M^T (own 4 columns)
  __shared__ float red[8];
  __shared__ float dinv[NN];
  __shared__ float accL[NCOLS*NN];
  __shared__ float hL[NCOLS*NN];     // own-column staging between GEMM and GCN
  __shared__ float gv[256], zv[128], t1v[256];
  __shared__ float colstat[2*NCOLS];

  // ---------------- E0: degrees (redundant per block) + GEMM1 x@W1 ----------
  for (int i = tid; i < NN; i += TPB) accL[i] = 1.0f;           // self loop
  __syncthreads();
  for (int e = tid; e < 800; e += TPB) atomicAdd(&accL[ei[800+e]], 1.0f);
  __syncthreads();
  for (int i = tid; i < NN; i += TPB) dinv[i] = 1.0f/sqrtf(accL[i]);
  __syncthreads();

  for (int u = tid; u < NCOLS*NN; u += TPB){
    int cl = u/NN, i = u - cl*NN, c = p + PBLK*cl;
    if (c < 256){
      float s = 0.f;
      for (int k = 0; k < 64; k++) s += x[i*64+k]*W1[k*256+c];
      hL[u] = s;
    }
  }
  __syncthreads();
  gcn_bn_relu(hL, hT, b1, g1, bt1, ei, dinv, accL, colstat, p, tid);
  gbar(ctr, 1*PBLK);                                   // hT complete (all cols)

  // ---------------- E2: GEMM2 h@W2 (reads all cols of hT) -------------------
  for (int u = tid; u < 20*NCOLS; u += TPB){
    int cl = u/20, iq = u - cl*20, c = p + PBLK*cl;
    if (c < 256){
      int i0 = 4*iq;
      float a0=0.f,a1=0.f,a2=0.f,a3=0.f;
      for (int k = 0; k < 256; k++){
        float wv = W2[k*256+c];
        float4 hv = *(const float4*)&hT[k*NN+i0];
        a0 += hv.x*wv; a1 += hv.y*wv; a2 += hv.z*wv; a3 += hv.w*wv;
      }
      hL[cl*NN+i0+0]=a0; hL[cl*NN+i0+1]=a1; hL[cl*NN+i0+2]=a2; hL[cl*NN+i0+3]=a3;
    }
  }
  __syncthreads();
  gcn_bn_relu(hL, h2T, b2, g2, bt2, ei, dinv, accL, colstat, p, tid);
  gbar(ctr, 2*PBLK);                                   // h2T complete

  // ---------------- E4: pool -> z -> t1 -> pair logits -> B -----------------
  for (int c = tid; c < 256; c += TPB){
    const float* r = &h2T[c*NN];
    float s = 0.f;
    for (int i = 0; i < NN; i++) s += r[i];
    gv[c] = s*(1.0f/NN);
  }
  __syncthreads();
  for (int c = tid; c < 128; c += TPB){
    float smu = bmu[c], slv = blv[c];
    for (int k = 0; k < 256; k++){
      float g = gv[k];
      smu += g*Wmu[k*128+c];
      slv += g*Wlv[k*128+c];
    }
    slv = fminf(fmaxf(slv, -4.f), 4.f);
    zv[c] = smu + eps[c]*expf(0.5f*slv);
  }
  __syncthreads();
  for (int c = tid; c < 256; c += TPB){
    float s = be1[c];
    for (int k = 0; k < 128; k++) s += zv[k]*We1[k*256+c];
    t1v[c] = fmaxf(s, 0.f);
  }
  __syncthreads();
  for (int r = 0; r < 4; r++){
    int i = p + PBLK*r;                                // rows p, p+20, p+40, p+60
    if (tid == 0) Bm[i*NN+i] = 1.0f;                   // diag forced to 1
    for (int j = i+1+tid; j < NN; j += TPB){
      int off = i*(2*NN-1-i)/2 + (j-i-1);              // triu(k=1) flat index
      float s = be2[off];
      for (int k = 0; k < 256; k++) s += t1v[k]*We2[k*3160+off];
      float sg = 1.0f/(1.0f + expf(-s));
      Bm[i*NN+j] = sg;
      Bm[j*NN+i] = sg;
    }
  }
  gbar(ctr, 3*PBLK);                                   // Bm complete

  // ---------------- E5: per-lane register caches for the MPM loop -----------
  const int w  = tid >> 6;
  const int l  = tid & 63;
  const int il = 16*w + (l & 15);    // this lane's row i (== j in M phase)
  const int ae = l >> 4;             // local column index 0..3
  const int al = 4*p + ae;           // this lane's column a

  float4 Af[20], Bf[20];
  float degA = 0.f, degB = 0.f;
  #pragma unroll
  for (int c = 0; c < 20; c++){
    int j0 = 4*c;
    int4 ar = *(const int4*)&adj[il*NN+j0];
    int q0 = adj[(j0+0)*NN+il];
    int q1 = adj[(j0+1)*NN+il];
    int q2 = adj[(j0+2)*NN+il];
    int q3 = adj[(j0+3)*NN+il];
    float4 a;
    a.x = ((ar.x|q0) != 0 || il == j0+0) ? 1.f : 0.f;
    a.y = ((ar.y|q1) != 0 || il == j0+1) ? 1.f : 0.f;
    a.z = ((ar.z|q2) != 0 || il == j0+2) ? 1.f : 0.f;
    a.w = ((ar.w|q3) != 0 || il == j0+3) ? 1.f : 0.f;
    Af[c] = a;
    degA += (a.x+a.y)+(a.z+a.w);
  }
  #pragma unroll
  for (int c = 0; c < 20; c++){
    float4 b = *(const float4*)&Bm[al*NN+4*c];
    Bf[c] = b;
    degB += (b.x+b.y)+(b.z+b.w);
  }
  const float ns = 1.0f/(fabsf(degA-degB)+1.0f);
  // b==a exclusion: zero B[a][a] in the register cache (valid since X,B >= 0)
  #pragma unroll
  for (int c = 0; c < 20; c++){
    if (c == p){
      if      (ae == 0) Bf[c].x = 0.f;
      else if (ae == 1) Bf[c].y = 0.f;
      else if (ae == 2) Bf[c].z = 0.f;
      else              Bf[c].w = 0.f;
    }
  }

  // ---------------- MPM: 50 iterations, 1 device barrier each ---------------
  for (int u = tid; u < NN*RP; u += TPB) Xs[u] = 1.0f/NN;   // X0 = 1/n
  float xn = 0.f;
  int bar = 3;
  for (int t = 0; t < 50; t++){
    if (t > 0){
      const float* Xsrc = ((t-1)&1) ? Xb1 : Xb0;
      for (int u = tid; u < NN*20; u += TPB){
        int j = u/20, c4 = (u - j*20)*4;
        *(float4*)&Xs[j*RP+c4] = *(const float4*)&Xsrc[j*NN+c4];
      }
    }
    __syncthreads();
    float sc = 1.0f;
    if (t > 0)
      sc = 1.0f/sqrtf(__hip_atomic_load(&sumsq[t], __ATOMIC_RELAXED, __HIP_MEMORY_SCOPE_AGENT));

    // M[il][al] = max_{b != al} X[il][b]*B[al][b]
    float m = 0.f;
    #pragma unroll
    for (int c = 0; c < 20; c++){
      float4 xv = *(const float4*)&Xs[il*RP+4*c];
      float p0 = xv.x*Bf[c].x, p1 = xv.y*Bf[c].y, p2 = xv.z*Bf[c].z, p3 = xv.w*Bf[c].w;
      m = fmaxf(m, fmaxf(fmaxf(p0,p1), fmaxf(p2,p3)));
    }
    float xnode = Xs[il*RP+al];
    MtL[ae*RP+il] = m;
    __syncthreads();

    // edge[il][al] = sum_j A[il][j]*M[j][al] - M[il][al]   (A[i][i] = 1)
    float e0=0.f,e1=0.f,e2=0.f,e3=0.f;
    #pragma unroll
    for (int c = 0; c < 20; c++){
      float4 mv = *(const float4*)&MtL[ae*RP+4*c];
      e0 += Af[c].x*mv.x; e1 += Af[c].y*mv.y; e2 += Af[c].z*mv.z; e3 += Af[c].w*mv.w;
    }
    float edge = ((e0+e1)+(e2+e3)) - m;
    xn = sc*(ns*xnode + edge);          // R_{t+1} = f(R_t / ||R_t||)

    if (t < 49){
      float* Xdst = (t&1) ? Xb1 : Xb0;
      Xdst[il*NN+al] = xn;
    }
    float v = wave_sum(xn*xn);
    if (l == 0) red[w] = v;
    __syncthreads();
    if (tid == 0){
      float tot = ((red[0]+red[1])+(red[2]+red[3]))+red[4];
      __hip_atomic_fetch_add(&sumsq[t+1], tot, __ATOMIC_RELAXED, __HIP_MEMORY_SCOPE_AGENT);
    }
    bar++;
    gbar(ctr, bar*PBLK);
  }
  float sf = 1.0f/sqrtf(__hip_atomic_load(&sumsq[50], __ATOMIC_RELAXED, __HIP_MEMORY_SCOPE_AGENT));
  out[il*NN+al] = xn*sf;
}

extern "C" void kernel_launch(void* const* d_in, const int* in_sizes, int n_in,
                              void* d_out, int out_size, void* d_ws, size_t ws_size,
                              hipStream_t stream)
{
  (void)in_sizes; (void)n_in; (void)out_size; (void)ws_size;
  // zero barrier counter + sumsq slots (re-poisoned to 0xAA before every launch)
  hipMemsetAsync(d_ws, 0, 512, stream);
  gvae_fused<<<PBLK, TPB, 0, stream>>>(
      (const float*)d_in[0],  (const int*)d_in[1],   (const int*)d_in[2],   (const float*)d_in[3],
      (const float*)d_in[4],  (const float*)d_in[5],  (const float*)d_in[6],  (const float*)d_in[7],
      (const float*)d_in[8],  (const float*)d_in[9],  (const float*)d_in[10], (const float*)d_in[11],
      (const float*)d_in[12], (const float*)d_in[13], (const float*)d_in[14], (const float*)d_in[15],
      (const float*)d_in[16], (const float*)d_in[17], (const float*)d_in[18], (const float*)d_in[19],
      (float*)d_out, (float*)d_ws);
}